// Round 5
// baseline (729.481 us; speedup 1.0000x reference)
//
#include <hip/hip_runtime.h>

// ===================== helpers =====================

__device__ __forceinline__ float bnscale(float g){ return g / sqrtf(1.0f + 1e-5f); }

__device__ __forceinline__ float conv_feat6(float p0,float p1,float p2,float p3,float p4,float p5,
                                            float w0,float w1,float w2,float w3,float w4,float w5,
                                            float sc,float bs){
    float y = p0*w0;
    y = fmaf(p1,w1,y); y = fmaf(p2,w2,y); y = fmaf(p3,w3,y);
    y = fmaf(p4,w4,y); y = fmaf(p5,w5,y);
    return fmaxf(fmaf(y,sc,bs), 0.0f);
}

// FPS distance: matches jnp.sum((p-c)**2, -1) left-to-right, NO contraction
__device__ __forceinline__ float fpsdist(float dx,float dy,float dz){
    #pragma clang fp contract(off)
    return (dx*dx + dy*dy) + dz*dz;
}

// square_distance(): d = (-2*dot + |q|^2) + |p|^2, left-to-right, NO contraction.
__device__ __forceinline__ float sumsq3(float x,float y,float z){
    #pragma clang fp contract(off)
    return (x*x + y*y) + z*z;
}
__device__ __forceinline__ float sqdist3(float qx,float qy,float qz,float qs,
                                         float px,float py,float pz){
    #pragma clang fp contract(off)
    {
        float dot = (qx*px + qy*py) + qz*pz;
        float pn  = (px*px + py*py) + pz*pz;
        return (-2.0f*dot + qs) + pn;
    }
}

// pack (dist,idx) into sortable u64: ascending u64 == ascending (dist, idx) lexicographic
__device__ __forceinline__ unsigned long long packdi(float d, unsigned int idx){
    unsigned int u = __float_as_uint(d);
    unsigned int msk = (unsigned int)((int)u >> 31);
    u ^= (msk | 0x80000000u);
    return ((unsigned long long)u << 32) | (unsigned long long)idx;
}

__device__ __forceinline__ unsigned long long u64min(unsigned long long a, unsigned long long b){
    return a < b ? a : b;
}

__device__ __forceinline__ unsigned long long u64_shfl_down(unsigned long long v, int off){
    unsigned int lo = (unsigned int)v, hi = (unsigned int)(v >> 32);
    lo = __shfl_down(lo, off, 64);
    hi = __shfl_down(hi, off, 64);
    return ((unsigned long long)hi << 32) | (unsigned long long)lo;
}

__device__ __forceinline__ unsigned long long u64_bcast0(unsigned long long v){
    unsigned int lo = (unsigned int)v, hi = (unsigned int)(v >> 32);
    lo = __shfl(lo, 0, 64);
    hi = __shfl(hi, 0, 64);
    return ((unsigned long long)hi << 32) | (unsigned long long)lo;
}

// ===================== k_fps1 =====================
// Merged center-compute + FPS(16384->128). One block (512 thr) per batch.
// v4: launch_bounds(512,1) -> 256 VGPR budget (v3's (512,2) = 128 budget
// forced px/py/pz/dist[32] to spill; VGPR_Count=108 + scratch was the tell).
// In-loop argmax tracks the small slot index i (inline-const cndmask);
// flat index reconstructed once per iteration.
__global__ __launch_bounds__(512, 1) void k_fps1(const float* __restrict__ xyz,
                                                 float* __restrict__ center,
                                                 float* __restrict__ out,
                                                 int* __restrict__ idx_out){
    constexpr int NTH = 512, PPT = 32, N = 16384, NPOINT = 128, NW = 8;
    int b = blockIdx.x, t = threadIdx.x;
    int wid = t>>6, lane = t&63;

    __shared__ float s_red[NW][3];
    __shared__ unsigned int s_khi[2][NW], s_klo[2][NW];

    const float* xb = xyz + (size_t)b*N*3;
    float px[PPT], py[PPT], pz[PPT], dist[PPT];
    #pragma unroll
    for (int i=0;i<PPT;i++){
        const float* sp = xb + (size_t)(t + i*NTH)*3;
        px[i]=sp[0]; py[i]=sp[1]; pz[i]=sp[2];
        dist[i]=1e10f;
    }
    // ---- block mean (center) ----
    float sx=0.f, sy=0.f, sz=0.f;
    #pragma unroll
    for (int i=0;i<PPT;i++){ sx+=px[i]; sy+=py[i]; sz+=pz[i]; }
    #pragma unroll
    for (int off=32; off>=1; off>>=1){
        sx += __shfl_down(sx, off, 64);
        sy += __shfl_down(sy, off, 64);
        sz += __shfl_down(sz, off, 64);
    }
    if (lane==0){ s_red[wid][0]=sx; s_red[wid][1]=sy; s_red[wid][2]=sz; }
    __syncthreads();
    float cx0=0.f, cy0=0.f, cz0=0.f;
    #pragma unroll
    for (int w2=0; w2<NW; ++w2){ cx0+=s_red[w2][0]; cy0+=s_red[w2][1]; cz0+=s_red[w2][2]; }
    cx0 *= (1.0f/16384.0f); cy0 *= (1.0f/16384.0f); cz0 *= (1.0f/16384.0f);
    if (t < 3){
        float c = (t==0)?cx0:((t==1)?cy0:cz0);
        center[b*3+t] = c;
        out[b*3+t] = c;           // output 0: center (32,3)
    }
    #pragma unroll
    for (int i=0;i<PPT;i++){ px[i]-=cx0; py[i]-=cy0; pz[i]-=cz0; }
    if (t==0) idx_out[b*NPOINT] = 0;

    float cx = xb[0]-cx0, cy = xb[1]-cy0, cz = xb[2]-cz0;

    for (int it=1; it<NPOINT; ++it){
        int par = it & 1;
        // ---- dist update + in-thread argmax (small-slot index) ----
        float bv = -1.0f; int bis = 0;
        #pragma unroll
        for (int i=0;i<PPT;i++){
            float d = fpsdist(px[i]-cx, py[i]-cy, pz[i]-cz);
            float nd = fminf(dist[i], d);
            dist[i] = nd;
            bool better = nd > bv;          // strict > : lowest slot wins in-thread
            bv  = better ? nd : bv;
            bis = better ? i  : bis;        // i is an inline const per unrolled step
        }
        int bi = t + (bis<<9);              // flat index (NTH=512)
        // ---- key-only wave reduce (bv>=0 so raw bits order; ~bi -> lowest idx wins) ----
        unsigned long long key = ((unsigned long long)__float_as_uint(bv) << 32)
                               | (unsigned long long)(unsigned)(~(unsigned)bi);
        #pragma unroll
        for (int off=32; off>=1; off>>=1){
            unsigned long long ok = u64_shfl_down(key, off);
            key = ok > key ? ok : key;
        }
        if (lane==0){ s_khi[par][wid]=(unsigned)(key>>32); s_klo[par][wid]=(unsigned)key; }
        __syncthreads();
        unsigned long long gk = ((unsigned long long)s_khi[par][0] << 32) | s_klo[par][0];
        #pragma unroll
        for (int w2=1; w2<NW; ++w2){
            unsigned long long k2 = ((unsigned long long)s_khi[par][w2] << 32) | s_klo[par][w2];
            if (k2 > gk) gk = k2;
        }
        int gi = (int)(~(unsigned)(gk & 0xFFFFFFFFull));
        gi = __builtin_amdgcn_readfirstlane(gi);
        if (t==0) idx_out[b*NPOINT + it] = gi;
        const float* wp = xb + (size_t)gi*3;
        cx = wp[0]-cx0; cy = wp[1]-cy0; cz = wp[2]-cz0;
    }
}

// ===================== k_knn1 v2 (fused gather1 + knn) =====================
// ONE WAVE per query (4 per block). No LDS, no barriers, no dead lanes.
// 256 residue-class minima (class = pt & 255) live in 4 u64 registers/lane:
// lane L owns classes {L, L+64, L+128, L+192} (slot = class>>6). Per round:
// global min via 3 u64min + 6-step shuffle; winning class rescanned by all
// 64 lanes (pt = c + 256*lane) with threshold exclusion (packed <= win);
// owner lane updates its register slot. Distances use the same sqdist3 as
// the proven round-4 kernel -> bit-identical selections.
__global__ __launch_bounds__(256) void k_knn1(const float* __restrict__ xyz,
                                              const float* __restrict__ f,
                                              const float* __restrict__ center,
                                              const float* __restrict__ conv1_w,
                                              const float* __restrict__ bn1_g,
                                              const float* __restrict__ bn1_b,
                                              const int* __restrict__ fps_idx,
                                              float* __restrict__ new_xyz,
                                              float* __restrict__ np_feat,
                                              int* __restrict__ knn_idx){
    int t = threadIdx.x, wid = t>>6, lane = t&63;
    int q = blockIdx.x*4 + wid;           // 0..4095
    int b = q>>7, s = q&127;

    float cx = center[b*3+0], cy = center[b*3+1], cz = center[b*3+2];
    int idx = fps_idx[b*128+s];
    const float* xp = xyz + ((size_t)b*16384 + idx)*3;
    const float* fp = f   + ((size_t)b*16384 + idx)*3;
    float p0 = xp[0]-cx, p1 = xp[1]-cy, p2 = xp[2]-cz;
    float p3 = fp[0], p4 = fp[1], p5 = fp[2];

    // --- gather1 work: conv feature (chan = lane) + new_xyz ---
    {
        const float* w6 = conv1_w + lane*6;
        float v = conv_feat6(p0,p1,p2,p3,p4,p5, w6[0],w6[1],w6[2],w6[3],w6[4],w6[5],
                             bnscale(bn1_g[lane]), bn1_b[lane]);
        np_feat[(size_t)q*64 + lane] = v;
        if (lane < 3){
            float pc = (lane==0)?p0:((lane==1)?p1:p2);
            new_xyz[(size_t)q*3 + lane] = pc;
        }
    }

    float qx = p0, qy = p1, qz = p2;
    float qs = sumsq3(qx,qy,qz);
    const float* xb = xyz + (size_t)b*16384*3;

    // --- phase 1: scan all 16384 pts; class minima in 4 registers ---
    unsigned long long m0=~0ull, m1=~0ull, m2=~0ull, m3=~0ull;
    for (int i=0; i<256; i+=4){
        #pragma unroll
        for (int j=0;j<4;j++){
            int n = lane + ((i+j)<<6);
            const float* p = xb + (size_t)n*3;
            float dx = p[0]-cx, dy = p[1]-cy, dz = p[2]-cz;
            float d = sqdist3(qx,qy,qz,qs,dx,dy,dz);
            unsigned long long pk = packdi(d,(unsigned)n);
            if (j==0) m0 = u64min(m0,pk);
            else if (j==1) m1 = u64min(m1,pk);
            else if (j==2) m2 = u64min(m2,pk);
            else m3 = u64min(m3,pk);
        }
    }

    // --- 32 extract-min rounds ---
    size_t kbase = (size_t)q*32;
    for (int r=0; r<32; ++r){
        unsigned long long mm = u64min(u64min(m0,m1), u64min(m2,m3));
        #pragma unroll
        for (int off=32; off>=1; off>>=1) mm = u64min(mm, u64_shfl_down(mm, off));
        unsigned long long win = u64_bcast0(mm);
        unsigned int widx = (unsigned int)(win & 0xFFFFFFFFull);
        if (lane==0) knn_idx[kbase + r] = (int)widx;
        int c = (int)(widx & 255u);
        // rescan class c (pts c + 256k) excluding everything selected so far
        int n2 = c + (lane<<8);
        const float* p = xb + (size_t)n2*3;
        float dx = p[0]-cx, dy = p[1]-cy, dz = p[2]-cz;
        float d = sqdist3(qx,qy,qz,qs,dx,dy,dz);
        unsigned long long pk = packdi(d,(unsigned)n2);
        if (pk <= win) pk = ~0ull;
        #pragma unroll
        for (int off=32; off>=1; off>>=1) pk = u64min(pk, u64_shfl_down(pk, off));
        unsigned long long nm = u64_bcast0(pk);
        int owner = c & 63, slot = c >> 6;
        if (lane == owner){
            if (slot==0) m0 = nm;
            else if (slot==1) m1 = nm;
            else if (slot==2) m2 = nm;
            else m3 = nm;
        }
    }
}

// ===================== k_group_local (round-4, unchanged) =====================
template<int K, int NQ, int NSRC, bool RECOMP>
__global__ __launch_bounds__(256, 2) void k_group_local(
    const float* __restrict__ xyz, const float* __restrict__ f, const float* __restrict__ center,
    const float* __restrict__ conv1_w, const float* __restrict__ bn1_g, const float* __restrict__ bn1_b,
    const float* __restrict__ src_feat,
    const int* __restrict__ knn_idx, const float* __restrict__ np_feat,
    const float* __restrict__ w, const float* __restrict__ g, const float* __restrict__ bb,
    float* __restrict__ out)
{
    __shared__ float wt[128*65];
    __shared__ float s_sc[64], s_bs[64];
    __shared__ float cwT[6*64];
    __shared__ float s_csc[64], s_cbs[64];
    __shared__ float np_l[4][64];
    __shared__ float gda[4][K][64];
    __shared__ float s_pts[4][K][6];

    int t = threadIdx.x;
    for (int e=t; e<8192; e+=256){ int o = e>>7, d = e&127; wt[d*65 + o] = w[e]; }
    if (t < 64){ s_sc[t] = bnscale(g[t]); s_bs[t] = bb[t]; }
    if constexpr (RECOMP){
        for (int e=t; e<384; e+=256){ int o = e/6, j = e%6; cwT[j*64 + o] = conv1_w[e]; }
        if (t < 64){ s_csc[t] = bnscale(bn1_g[t]); s_cbs[t] = bn1_b[t]; }
    }
    __syncthreads();

    int wid = t>>6, lane = t&63;
    int q = blockIdx.x*4 + wid;
    int b = q / NQ, s = q % NQ;

    float np_o = np_feat[((size_t)b*NQ + s)*64 + lane];
    np_l[wid][lane] = np_o;

    const int* kix = knn_idx + ((size_t)b*NQ + s)*K;

    if constexpr (RECOMP){
        float cx = center[b*3+0], cy = center[b*3+1], cz = center[b*3+2];
        if (lane < K){
            int myi = kix[lane];
            const float* xp = xyz + ((size_t)b*16384 + myi)*3;
            s_pts[wid][lane][0] = xp[0]-cx;
            s_pts[wid][lane][1] = xp[1]-cy;
            s_pts[wid][lane][2] = xp[2]-cz;
            const float* fp = f + ((size_t)b*16384 + myi)*3;
            s_pts[wid][lane][3] = fp[0];
            s_pts[wid][lane][4] = fp[1];
            s_pts[wid][lane][5] = fp[2];
        }
        #pragma unroll
        for (int k=0; k<K; ++k){
            float gv = conv_feat6(s_pts[wid][k][0], s_pts[wid][k][1], s_pts[wid][k][2],
                                  s_pts[wid][k][3], s_pts[wid][k][4], s_pts[wid][k][5],
                                  cwT[0*64+lane], cwT[1*64+lane], cwT[2*64+lane],
                                  cwT[3*64+lane], cwT[4*64+lane], cwT[5*64+lane],
                                  s_csc[lane], s_cbs[lane]);
            gda[wid][k][lane] = gv - np_o;
        }
    } else {
        int myi = kix[lane < K ? lane : 0];
        #pragma unroll
        for (int k=0; k<K; ++k){
            int ik = __shfl(myi, k, 64);
            gda[wid][k][lane] = src_feat[((size_t)b*NSRC + ik)*64 + lane] - np_o;
        }
    }

    float C = 0.f;
    #pragma unroll
    for (int d=0; d<64; d++) C = fmaf(np_l[wid][d], wt[(64+d)*65 + lane], C);

    float acc_y[K];
    #pragma unroll
    for (int k=0;k<K;k++) acc_y[k] = C;

    #pragma unroll
    for (int c=0; c<2; ++c){
        float wr[32];
        #pragma unroll
        for (int j=0;j<32;j++) wr[j] = wt[(c*32+j)*65 + lane];
        #pragma unroll
        for (int k=0;k<K;k++){
            const float4* g4 = (const float4*)&gda[wid][k][c*32];
            float yk = 0.f;
            #pragma unroll
            for (int j4=0;j4<8;j4++){
                float4 gg = g4[j4];
                yk = fmaf(gg.x, wr[j4*4+0], yk);
                yk = fmaf(gg.y, wr[j4*4+1], yk);
                yk = fmaf(gg.z, wr[j4*4+2], yk);
                yk = fmaf(gg.w, wr[j4*4+3], yk);
            }
            acc_y[k] = acc_y[k] + yk;
        }
    }

    float acc = -1e30f;
    #pragma unroll
    for (int k=0;k<K;k++){
        float v = fmaxf(fmaf(acc_y[k], s_sc[lane], s_bs[lane]), 0.0f);
        acc = fmaxf(acc, v);
    }
    out[((size_t)b*NQ + s)*64 + lane] = acc;
}

// ===================== sa_block =====================
__device__ void sa_block(const float* X, float* Xout,
                         float* Q, float* E, float* XV, float* XR, float* CS,
                         const float* qk_w, const float* v_w, const float* v_b,
                         const float* t_w, const float* t_b,
                         const float* g, const float* bb, int t)
{
    for (int e=t; e<512; e+=256){
        int n = e>>4, o = e&15;
        float y = 0.f;
        for (int c=0;c<64;c++) y = fmaf(qk_w[o*64+c], X[c*32+n], y);
        Q[n*16+o] = y;
    }
    for (int e=t; e<2048; e+=256){
        int o = e>>5, n = e&31;
        float y = v_b[o];
        for (int c=0;c<64;c++) y = fmaf(v_w[o*64+c], X[c*32+n], y);
        XV[o*32+n] = y;
    }
    __syncthreads();
    for (int e=t; e<1024; e+=256){
        int n = e>>5, m = e&31;
        float y = 0.f;
        for (int d=0;d<16;d++) y = fmaf(Q[n*16+d], Q[m*16+d], y);
        E[e] = y;
    }
    __syncthreads();
    if (t < 32){
        float mx = -1e30f;
        for (int m=0;m<32;m++) mx = fmaxf(mx, E[t*32+m]);
        float sum = 0.f;
        for (int m=0;m<32;m++){ float v = expf(E[t*32+m]-mx); E[t*32+m]=v; sum += v; }
        for (int m=0;m<32;m++) E[t*32+m] = E[t*32+m] / sum;
    }
    __syncthreads();
    if (t < 32){
        float cs = 0.f;
        for (int n=0;n<32;n++) cs += E[n*32+t];
        CS[t] = 1e-9f + cs;
    }
    __syncthreads();
    for (int e=t; e<1024; e+=256) E[e] = E[e] / CS[e&31];
    __syncthreads();
    for (int e=t; e<2048; e+=256){
        int c = e>>5, m = e&31;
        float y = 0.f;
        for (int n=0;n<32;n++) y = fmaf(XV[c*32+n], E[n*32+m], y);
        XR[c*32+m] = y;
    }
    __syncthreads();
    for (int e=t; e<2048; e+=256){
        int o = e>>5, n = e&31;
        float y = 0.f;
        for (int c=0;c<64;c++) y = fmaf(t_w[o*64+c], X[c*32+n]-XR[c*32+n], y);
        y += t_b[o];
        y = fmaxf(fmaf(y, bnscale(g[o]), bb[o]), 0.0f);
        Xout[e] = X[e] + y;
    }
    __syncthreads();
}

// ===================== k_mega =====================
// fps2 + gather2 + knn2 + group_local<16> + tail, fused. One block per batch.
// All intermediates (fps2 idx, np2, knn2, f1) stay in LDS.
__global__ __launch_bounds__(256) void k_mega(
    const float* __restrict__ new_xyz1,   // (b,128,3) centered
    const float* __restrict__ feat,       // (b,128,64)
    const float* __restrict__ l1_w, const float* __restrict__ l1_g, const float* __restrict__ l1_b,
    const float* st_c1_w, const float* st_bn1_g, const float* st_bn1_b,
    const float* st_c2_w, const float* st_bn2_g, const float* st_bn2_b,
    const float* sa1_qk, const float* sa1_v, const float* sa1_vb,
    const float* sa1_t, const float* sa1_tb, const float* sa1_g, const float* sa1_b,
    const float* sa2_qk, const float* sa2_v, const float* sa2_vb,
    const float* sa2_t, const float* sa2_tb, const float* sa2_g, const float* sa2_b,
    const float* fuse_w, const float* fuse_g, const float* fuse_b,
    const float* lin1_w, const float* bn6_g, const float* bn6_b,
    const float* lin2_w, const float* lin2_b,
    float* __restrict__ out)
{
    __shared__ float nx1[384];            // new_xyz1[b] (128,3)
    __shared__ int   s_i2[32];            // fps2 indices
    __shared__ float np2L[2048];          // np2 (32,64)
    __shared__ float nx2[96];             // new_xyz2 (32,3)
    __shared__ int   s_k2[512];           // knn2 (32,16)
    __shared__ float wt[8320];            // l1_w transposed, stride 65
    __shared__ float s_sc[64], s_bs[64];
    __shared__ float gdaL[4][16][64];
    __shared__ float smt[14848];          // tail scratch; F1 at offset 0

    int b = blockIdx.x, t = threadIdx.x, wid = t>>6, lane = t&63;

    // ---- A: stage nx1 + wt + bn consts ----
    for (int e=t; e<384; e+=256) nx1[e] = new_xyz1[(size_t)b*384 + e];
    for (int e=t; e<8192; e+=256){ int o = e>>7, d = e&127; wt[d*65 + o] = l1_w[e]; }
    if (t < 64){ s_sc[t] = bnscale(l1_g[t]); s_bs[t] = l1_b[t]; }
    __syncthreads();

    // ---- B: fps2 (128 -> 32), wave 0 only, proven k_fps2 body on LDS ----
    if (wid == 0){
        float px[2],py[2],pz[2],dist[2];
        #pragma unroll
        for (int i=0;i<2;i++){
            int n = lane + i*64;
            px[i]=nx1[n*3+0]; py[i]=nx1[n*3+1]; pz[i]=nx1[n*3+2];
            dist[i]=1e10f;
        }
        if (lane==0) s_i2[0] = 0;
        float cx=nx1[0], cy=nx1[1], cz=nx1[2];
        for (int it=1; it<32; ++it){
            float bv=-1.0f; int bi=0;
            float bx=0.f, by=0.f, bz=0.f;
            #pragma unroll
            for (int i=0;i<2;i++){
                float d = fpsdist(px[i]-cx, py[i]-cy, pz[i]-cz);
                float nd = fminf(dist[i], d);
                dist[i]=nd;
                bool better = nd > bv;
                bv = better ? nd : bv;
                bi = better ? (lane + i*64) : bi;
                bx = better ? px[i] : bx;
                by = better ? py[i] : by;
                bz = better ? pz[i] : bz;
            }
            unsigned long long key = ((unsigned long long)__float_as_uint(bv) << 32)
                                   | (unsigned long long)(unsigned)(~(unsigned)bi);
            #pragma unroll
            for (int off=32; off>=1; off>>=1){
                unsigned long long ok = u64_shfl_down(key, off);
                float ox = __shfl_down(bx, off, 64);
                float oy = __shfl_down(by, off, 64);
                float oz = __shfl_down(bz, off, 64);
                bool better = ok > key;
                key = better ? ok : key;
                bx = better ? ox : bx;
                by = better ? oy : by;
                bz = better ? oz : bz;
            }
            key = u64_bcast0(key);
            cx = __shfl(bx, 0, 64); cy = __shfl(by, 0, 64); cz = __shfl(bz, 0, 64);
            if (lane==0) s_i2[it] = (int)(~(unsigned)(key & 0xFFFFFFFFull));
        }
    }
    __syncthreads();

    // ---- C: gather2 (np2 + new_xyz2 into LDS) ----
    for (int e=t; e<2048; e+=256){
        int s = e>>6, o = e&63;
        np2L[s*64 + o] = feat[((size_t)b*128 + s_i2[s])*64 + o];
    }
    if (t < 32){
        int idx = s_i2[t];
        nx2[t*3+0] = nx1[idx*3+0];
        nx2[t*3+1] = nx1[idx*3+1];
        nx2[t*3+2] = nx1[idx*3+2];
    }
    __syncthreads();

    // ---- D: knn2 (32 queries x top-16 of 128), wave w -> queries wid+4j ----
    for (int j=0;j<8;j++){
        int s = wid + 4*j;
        float qx = nx2[s*3+0], qy = nx2[s*3+1], qz = nx2[s*3+2];
        float qs = sumsq3(qx,qy,qz);
        unsigned long long pp0, pp1;
        {
            float ax=nx1[lane*3+0], ay=nx1[lane*3+1], az=nx1[lane*3+2];
            pp0 = packdi(sqdist3(qx,qy,qz,qs,ax,ay,az), (unsigned)lane);
            ax=nx1[(lane+64)*3+0]; ay=nx1[(lane+64)*3+1]; az=nx1[(lane+64)*3+2];
            pp1 = packdi(sqdist3(qx,qy,qz,qs,ax,ay,az), (unsigned)(lane+64));
        }
        for (int r=0; r<16; ++r){
            unsigned long long mm = u64min(pp0, pp1);
            #pragma unroll
            for (int off=32; off>=1; off>>=1) mm = u64min(mm, u64_shfl_down(mm, off));
            unsigned long long win = u64_bcast0(mm);
            if (lane==0) s_k2[s*16 + r] = (int)(win & 0xFFFFFFFFull);
            if (pp0 == win) pp0 = ~0ull;
            if (pp1 == win) pp1 = ~0ull;
        }
    }
    __syncthreads();

    // ---- E: group_local<16> (proven math), output straight into F1 [c][n] ----
    for (int j=0;j<8;j++){
        int s = wid + 4*j;
        float np_o = np2L[s*64 + lane];
        #pragma unroll
        for (int k=0;k<16;k++){
            int ik = s_k2[s*16 + k];
            gdaL[wid][k][lane] = feat[((size_t)b*128 + ik)*64 + lane] - np_o;
        }
        float C0 = 0.f;
        #pragma unroll
        for (int d=0; d<64; d++) C0 = fmaf(np2L[s*64 + d], wt[(64+d)*65 + lane], C0);
        float acc_y[16];
        #pragma unroll
        for (int k=0;k<16;k++) acc_y[k] = C0;
        #pragma unroll
        for (int c=0; c<2; ++c){
            float wr[32];
            #pragma unroll
            for (int jj=0;jj<32;jj++) wr[jj] = wt[(c*32+jj)*65 + lane];
            #pragma unroll
            for (int k=0;k<16;k++){
                const float4* g4 = (const float4*)&gdaL[wid][k][c*32];
                float yk = 0.f;
                #pragma unroll
                for (int j4=0;j4<8;j4++){
                    float4 gg = g4[j4];
                    yk = fmaf(gg.x, wr[j4*4+0], yk);
                    yk = fmaf(gg.y, wr[j4*4+1], yk);
                    yk = fmaf(gg.z, wr[j4*4+2], yk);
                    yk = fmaf(gg.w, wr[j4*4+3], yk);
                }
                acc_y[k] = acc_y[k] + yk;
            }
        }
        float acc = -1e30f;
        #pragma unroll
        for (int k=0;k<16;k++){
            float v = fmaxf(fmaf(acc_y[k], s_sc[lane], s_bs[lane]), 0.0f);
            acc = fmaxf(acc, v);
        }
        smt[lane*32 + s] = acc;     // F1[c=lane][n=s]
    }
    __syncthreads();

    // ---- F: tail (round-4 k_tail body; F1 already resident) ----
    float* F1 = smt;
    float* XA = smt + 2048;
    float* XB = smt + 4096;
    float* Q  = smt + 6144;
    float* E  = smt + 6656;
    float* XV = smt + 7680;
    float* XR = smt + 9728;
    float* CS = smt + 11776;
    float* FO = smt + 6144;
    float* PO = smt + 14336;
    float* P2 = smt + 14592;

    for (int e=t; e<2048; e+=256){
        int o = e>>5, n = e&31;
        float y = 0.f;
        for (int c=0;c<64;c++) y = fmaf(st_c1_w[o*64+c], F1[c*32+n], y);
        XA[e] = fmaxf(fmaf(y, bnscale(st_bn1_g[o]), st_bn1_b[o]), 0.0f);
    }
    __syncthreads();
    for (int e=t; e<2048; e+=256){
        int o = e>>5, n = e&31;
        float y = 0.f;
        for (int c=0;c<64;c++) y = fmaf(st_c2_w[o*64+c], XA[c*32+n], y);
        XB[e] = fmaxf(fmaf(y, bnscale(st_bn2_g[o]), st_bn2_b[o]), 0.0f);
    }
    __syncthreads();
    sa_block(XB, XA, Q,E,XV,XR,CS, sa1_qk, sa1_v, sa1_vb, sa1_t, sa1_tb, sa1_g, sa1_b, t);
    sa_block(XA, XB, Q,E,XV,XR,CS, sa2_qk, sa2_v, sa2_vb, sa2_t, sa2_tb, sa2_g, sa2_b, t);
    for (int e=t; e<8192; e+=256){
        int o = e>>5, n = e&31;
        const float* wr = fuse_w + o*192;
        float y = 0.f;
        for (int c=0;c<64;c++) y = fmaf(wr[c],      XA[c*32+n], y);
        for (int c=0;c<64;c++) y = fmaf(wr[64+c],   XB[c*32+n], y);
        for (int c=0;c<64;c++) y = fmaf(wr[128+c],  F1[c*32+n], y);
        float v = fmaf(y, bnscale(fuse_g[o]), fuse_b[o]);
        FO[e] = (v > 0.0f) ? v : 0.2f*v;
    }
    __syncthreads();
    {
        float mx = -1e30f;
        for (int n=0;n<32;n++) mx = fmaxf(mx, FO[t*32+n]);
        PO[t] = mx;
    }
    __syncthreads();
    {
        const float* wr = lin1_w + t*256;
        float y = 0.f;
        for (int c=0;c<256;c++) y = fmaf(wr[c], PO[c], y);
        P2[t] = fmaxf(fmaf(y, bnscale(bn6_g[t]), bn6_b[t]), 0.0f);
    }
    __syncthreads();
    {
        const float* wr = lin2_w + t*256;
        float y = 0.f;
        for (int c=0;c<256;c++) y = fmaf(wr[c], P2[c], y);
        out[96 + b*256 + t] = y + lin2_b[t];
    }
}

// ===================== launch =====================
extern "C" void kernel_launch(void* const* d_in, const int* in_sizes, int n_in,
                              void* d_out, int out_size, void* d_ws, size_t ws_size,
                              hipStream_t stream)
{
    const float* xyz      = (const float*)d_in[0];
    const float* f        = (const float*)d_in[1];
    const float* conv1_w  = (const float*)d_in[2];
    const float* bn1_g    = (const float*)d_in[3];
    const float* bn1_b    = (const float*)d_in[4];
    const float* l0_w     = (const float*)d_in[5];
    const float* l0_g     = (const float*)d_in[6];
    const float* l0_b     = (const float*)d_in[7];
    const float* l1_w     = (const float*)d_in[8];
    const float* l1_g     = (const float*)d_in[9];
    const float* l1_b     = (const float*)d_in[10];
    const float* st_c1_w  = (const float*)d_in[11];
    const float* st_bn1_g = (const float*)d_in[12];
    const float* st_bn1_b = (const float*)d_in[13];
    const float* st_c2_w  = (const float*)d_in[14];
    const float* st_bn2_g = (const float*)d_in[15];
    const float* st_bn2_b = (const float*)d_in[16];
    const float* sa1_qk   = (const float*)d_in[17];
    const float* sa1_v    = (const float*)d_in[18];
    const float* sa1_vb   = (const float*)d_in[19];
    const float* sa1_t    = (const float*)d_in[20];
    const float* sa1_tb   = (const float*)d_in[21];
    const float* sa1_g    = (const float*)d_in[22];
    const float* sa1_b    = (const float*)d_in[23];
    const float* sa2_qk   = (const float*)d_in[24];
    const float* sa2_v    = (const float*)d_in[25];
    const float* sa2_vb   = (const float*)d_in[26];
    const float* sa2_t    = (const float*)d_in[27];
    const float* sa2_tb   = (const float*)d_in[28];
    const float* sa2_g    = (const float*)d_in[29];
    const float* sa2_b    = (const float*)d_in[30];
    const float* fuse_w   = (const float*)d_in[31];
    const float* fuse_g   = (const float*)d_in[32];
    const float* fuse_b   = (const float*)d_in[33];
    const float* lin1_w   = (const float*)d_in[34];
    const float* bn6_g    = (const float*)d_in[35];
    const float* bn6_b    = (const float*)d_in[36];
    const float* lin2_w   = (const float*)d_in[37];
    const float* lin2_b   = (const float*)d_in[38];
    float* out = (float*)d_out;

    float* ws = (float*)d_ws;
    float* center   = ws + 0;        // 96
    float* new_xyz1 = ws + 96;       // 12288
    float* np1      = ws + 12384;    // 262144
    float* feat     = ws + 274528;   // 262144
    int*   fps1     = (int*)(ws + 536672);  // 4096
    int*   knn1     = (int*)(ws + 540768);  // 131072

    k_fps1<<<32, 512, 0, stream>>>(xyz, center, out, fps1);
    k_knn1<<<1024, 256, 0, stream>>>(xyz, f, center, conv1_w, bn1_g, bn1_b,
                                     fps1, new_xyz1, np1, knn1);
    k_group_local<32,128,1,true><<<1024, 256, 0, stream>>>(
        xyz, f, center, conv1_w, bn1_g, bn1_b, nullptr, knn1, np1, l0_w, l0_g, l0_b, feat);
    k_mega<<<32, 256, 0, stream>>>(new_xyz1, feat,
        l1_w, l1_g, l1_b,
        st_c1_w, st_bn1_g, st_bn1_b, st_c2_w, st_bn2_g, st_bn2_b,
        sa1_qk, sa1_v, sa1_vb, sa1_t, sa1_tb, sa1_g, sa1_b,
        sa2_qk, sa2_v, sa2_vb, sa2_t, sa2_tb, sa2_g, sa2_b,
        fuse_w, fuse_g, fuse_b, lin1_w, bn6_g, bn6_b, lin2_w, lin2_b, out);
}

// Round 6
// 724.269 us; speedup vs baseline: 1.0072x; 1.0072x over previous
//
#include <hip/hip_runtime.h>

// ===================== helpers =====================

__device__ __forceinline__ float bnscale(float g){ return g / sqrtf(1.0f + 1e-5f); }

__device__ __forceinline__ float conv_feat6(float p0,float p1,float p2,float p3,float p4,float p5,
                                            float w0,float w1,float w2,float w3,float w4,float w5,
                                            float sc,float bs){
    float y = p0*w0;
    y = fmaf(p1,w1,y); y = fmaf(p2,w2,y); y = fmaf(p3,w3,y);
    y = fmaf(p4,w4,y); y = fmaf(p5,w5,y);
    return fmaxf(fmaf(y,sc,bs), 0.0f);
}

// FPS distance: matches jnp.sum((p-c)**2, -1) left-to-right, NO contraction
__device__ __forceinline__ float fpsdist(float dx,float dy,float dz){
    #pragma clang fp contract(off)
    return (dx*dx + dy*dy) + dz*dz;
}

// square_distance(): d = (-2*dot + |q|^2) + |p|^2, left-to-right, NO contraction.
__device__ __forceinline__ float sumsq3(float x,float y,float z){
    #pragma clang fp contract(off)
    return (x*x + y*y) + z*z;
}
__device__ __forceinline__ float sqdist3(float qx,float qy,float qz,float qs,
                                         float px,float py,float pz){
    #pragma clang fp contract(off)
    {
        float dot = (qx*px + qy*py) + qz*pz;
        float pn  = (px*px + py*py) + pz*pz;
        return (-2.0f*dot + qs) + pn;
    }
}

// pack (dist,idx) into sortable u64: ascending u64 == ascending (dist, idx) lexicographic
__device__ __forceinline__ unsigned long long packdi(float d, unsigned int idx){
    unsigned int u = __float_as_uint(d);
    unsigned int msk = (unsigned int)((int)u >> 31);
    u ^= (msk | 0x80000000u);
    return ((unsigned long long)u << 32) | (unsigned long long)idx;
}

__device__ __forceinline__ unsigned long long u64min(unsigned long long a, unsigned long long b){
    return a < b ? a : b;
}

__device__ __forceinline__ unsigned long long u64_shfl_down(unsigned long long v, int off){
    unsigned int lo = (unsigned int)v, hi = (unsigned int)(v >> 32);
    lo = __shfl_down(lo, off, 64);
    hi = __shfl_down(hi, off, 64);
    return ((unsigned long long)hi << 32) | (unsigned long long)lo;
}

__device__ __forceinline__ unsigned long long u64_bcast0(unsigned long long v){
    unsigned int lo = (unsigned int)v, hi = (unsigned int)(v >> 32);
    lo = __shfl(lo, 0, 64);
    hi = __shfl(hi, 0, 64);
    return ((unsigned long long)hi << 32) | (unsigned long long)lo;
}

// ===================== k_fps1 =====================
// Merged center-compute + FPS(16384->128). One block (1024 thr) per batch.
// v5: 1024 threads / PPT=16 -> 64-float working set fits ARCH VGPRs at
// (1024,1) cap 128 (round-4's VGPR_Count=108 < 128-float set proved AGPR
// shuffling at PPT=32); 4 waves/SIMD for issue overlap.
__global__ __launch_bounds__(1024, 1) void k_fps1(const float* __restrict__ xyz,
                                                  float* __restrict__ center,
                                                  float* __restrict__ out,
                                                  int* __restrict__ idx_out){
    constexpr int NTH = 1024, PPT = 16, N = 16384, NPOINT = 128, NW = 16;
    int b = blockIdx.x, t = threadIdx.x;
    int wid = t>>6, lane = t&63;

    __shared__ float s_red[NW][3];
    __shared__ unsigned int s_khi[2][NW], s_klo[2][NW];

    const float* xb = xyz + (size_t)b*N*3;
    float px[PPT], py[PPT], pz[PPT], dist[PPT];
    #pragma unroll
    for (int i=0;i<PPT;i++){
        const float* sp = xb + (size_t)(t + i*NTH)*3;
        px[i]=sp[0]; py[i]=sp[1]; pz[i]=sp[2];
        dist[i]=1e10f;
    }
    // ---- block mean (center) ----
    float sx=0.f, sy=0.f, sz=0.f;
    #pragma unroll
    for (int i=0;i<PPT;i++){ sx+=px[i]; sy+=py[i]; sz+=pz[i]; }
    #pragma unroll
    for (int off=32; off>=1; off>>=1){
        sx += __shfl_down(sx, off, 64);
        sy += __shfl_down(sy, off, 64);
        sz += __shfl_down(sz, off, 64);
    }
    if (lane==0){ s_red[wid][0]=sx; s_red[wid][1]=sy; s_red[wid][2]=sz; }
    __syncthreads();
    float cx0=0.f, cy0=0.f, cz0=0.f;
    #pragma unroll
    for (int w2=0; w2<NW; ++w2){ cx0+=s_red[w2][0]; cy0+=s_red[w2][1]; cz0+=s_red[w2][2]; }
    cx0 *= (1.0f/16384.0f); cy0 *= (1.0f/16384.0f); cz0 *= (1.0f/16384.0f);
    if (t < 3){
        float c = (t==0)?cx0:((t==1)?cy0:cz0);
        center[b*3+t] = c;
        out[b*3+t] = c;           // output 0: center (32,3)
    }
    #pragma unroll
    for (int i=0;i<PPT;i++){ px[i]-=cx0; py[i]-=cy0; pz[i]-=cz0; }
    if (t==0) idx_out[b*NPOINT] = 0;

    float cx = xb[0]-cx0, cy = xb[1]-cy0, cz = xb[2]-cz0;

    for (int it=1; it<NPOINT; ++it){
        int par = it & 1;
        float bv = -1.0f; int bis = 0;
        #pragma unroll
        for (int i=0;i<PPT;i++){
            float d = fpsdist(px[i]-cx, py[i]-cy, pz[i]-cz);
            float nd = fminf(dist[i], d);
            dist[i] = nd;
            bool better = nd > bv;          // strict > : lowest slot wins in-thread
            bv  = better ? nd : bv;
            bis = better ? i  : bis;
        }
        int bi = t + (bis<<10);             // flat index (NTH=1024)
        unsigned long long key = ((unsigned long long)__float_as_uint(bv) << 32)
                               | (unsigned long long)(unsigned)(~(unsigned)bi);
        #pragma unroll
        for (int off=32; off>=1; off>>=1){
            unsigned long long ok = u64_shfl_down(key, off);
            key = ok > key ? ok : key;
        }
        if (lane==0){ s_khi[par][wid]=(unsigned)(key>>32); s_klo[par][wid]=(unsigned)key; }
        __syncthreads();
        unsigned long long gk = ((unsigned long long)s_khi[par][0] << 32) | s_klo[par][0];
        #pragma unroll
        for (int w2=1; w2<NW; ++w2){
            unsigned long long k2 = ((unsigned long long)s_khi[par][w2] << 32) | s_klo[par][w2];
            if (k2 > gk) gk = k2;
        }
        int gi = (int)(~(unsigned)(gk & 0xFFFFFFFFull));
        gi = __builtin_amdgcn_readfirstlane(gi);
        if (t==0) idx_out[b*NPOINT + it] = gi;
        const float* wp = xb + (size_t)gi*3;
        cx = wp[0]-cx0; cy = wp[1]-cy0; cz = wp[2]-cz0;
    }
}

// ===================== k_knn1 (round-5, unchanged) =====================
__global__ __launch_bounds__(256) void k_knn1(const float* __restrict__ xyz,
                                              const float* __restrict__ f,
                                              const float* __restrict__ center,
                                              const float* __restrict__ conv1_w,
                                              const float* __restrict__ bn1_g,
                                              const float* __restrict__ bn1_b,
                                              const int* __restrict__ fps_idx,
                                              float* __restrict__ new_xyz,
                                              float* __restrict__ np_feat,
                                              int* __restrict__ knn_idx){
    int t = threadIdx.x, wid = t>>6, lane = t&63;
    int q = blockIdx.x*4 + wid;           // 0..4095
    int b = q>>7, s = q&127;

    float cx = center[b*3+0], cy = center[b*3+1], cz = center[b*3+2];
    int idx = fps_idx[b*128+s];
    const float* xp = xyz + ((size_t)b*16384 + idx)*3;
    const float* fp = f   + ((size_t)b*16384 + idx)*3;
    float p0 = xp[0]-cx, p1 = xp[1]-cy, p2 = xp[2]-cz;
    float p3 = fp[0], p4 = fp[1], p5 = fp[2];

    {
        const float* w6 = conv1_w + lane*6;
        float v = conv_feat6(p0,p1,p2,p3,p4,p5, w6[0],w6[1],w6[2],w6[3],w6[4],w6[5],
                             bnscale(bn1_g[lane]), bn1_b[lane]);
        np_feat[(size_t)q*64 + lane] = v;
        if (lane < 3){
            float pc = (lane==0)?p0:((lane==1)?p1:p2);
            new_xyz[(size_t)q*3 + lane] = pc;
        }
    }

    float qx = p0, qy = p1, qz = p2;
    float qs = sumsq3(qx,qy,qz);
    const float* xb = xyz + (size_t)b*16384*3;

    unsigned long long m0=~0ull, m1=~0ull, m2=~0ull, m3=~0ull;
    for (int i=0; i<256; i+=4){
        #pragma unroll
        for (int j=0;j<4;j++){
            int n = lane + ((i+j)<<6);
            const float* p = xb + (size_t)n*3;
            float dx = p[0]-cx, dy = p[1]-cy, dz = p[2]-cz;
            float d = sqdist3(qx,qy,qz,qs,dx,dy,dz);
            unsigned long long pk = packdi(d,(unsigned)n);
            if (j==0) m0 = u64min(m0,pk);
            else if (j==1) m1 = u64min(m1,pk);
            else if (j==2) m2 = u64min(m2,pk);
            else m3 = u64min(m3,pk);
        }
    }

    size_t kbase = (size_t)q*32;
    for (int r=0; r<32; ++r){
        unsigned long long mm = u64min(u64min(m0,m1), u64min(m2,m3));
        #pragma unroll
        for (int off=32; off>=1; off>>=1) mm = u64min(mm, u64_shfl_down(mm, off));
        unsigned long long win = u64_bcast0(mm);
        unsigned int widx = (unsigned int)(win & 0xFFFFFFFFull);
        if (lane==0) knn_idx[kbase + r] = (int)widx;
        int c = (int)(widx & 255u);
        int n2 = c + (lane<<8);
        const float* p = xb + (size_t)n2*3;
        float dx = p[0]-cx, dy = p[1]-cy, dz = p[2]-cz;
        float d = sqdist3(qx,qy,qz,qs,dx,dy,dz);
        unsigned long long pk = packdi(d,(unsigned)n2);
        if (pk <= win) pk = ~0ull;
        #pragma unroll
        for (int off=32; off>=1; off>>=1) pk = u64min(pk, u64_shfl_down(pk, off));
        unsigned long long nm = u64_bcast0(pk);
        int owner = c & 63, slot = c >> 6;
        if (lane == owner){
            if (slot==0) m0 = nm;
            else if (slot==1) m1 = nm;
            else if (slot==2) m2 = nm;
            else m3 = nm;
        }
    }
}

// ===================== k_group_local (round-4, unchanged) =====================
template<int K, int NQ, int NSRC, bool RECOMP>
__global__ __launch_bounds__(256, 2) void k_group_local(
    const float* __restrict__ xyz, const float* __restrict__ f, const float* __restrict__ center,
    const float* __restrict__ conv1_w, const float* __restrict__ bn1_g, const float* __restrict__ bn1_b,
    const float* __restrict__ src_feat,
    const int* __restrict__ knn_idx, const float* __restrict__ np_feat,
    const float* __restrict__ w, const float* __restrict__ g, const float* __restrict__ bb,
    float* __restrict__ out)
{
    __shared__ float wt[128*65];
    __shared__ float s_sc[64], s_bs[64];
    __shared__ float cwT[6*64];
    __shared__ float s_csc[64], s_cbs[64];
    __shared__ float np_l[4][64];
    __shared__ float gda[4][K][64];
    __shared__ float s_pts[4][K][6];

    int t = threadIdx.x;
    for (int e=t; e<8192; e+=256){ int o = e>>7, d = e&127; wt[d*65 + o] = w[e]; }
    if (t < 64){ s_sc[t] = bnscale(g[t]); s_bs[t] = bb[t]; }
    if constexpr (RECOMP){
        for (int e=t; e<384; e+=256){ int o = e/6, j = e%6; cwT[j*64 + o] = conv1_w[e]; }
        if (t < 64){ s_csc[t] = bnscale(bn1_g[t]); s_cbs[t] = bn1_b[t]; }
    }
    __syncthreads();

    int wid = t>>6, lane = t&63;
    int q = blockIdx.x*4 + wid;
    int b = q / NQ, s = q % NQ;

    float np_o = np_feat[((size_t)b*NQ + s)*64 + lane];
    np_l[wid][lane] = np_o;

    const int* kix = knn_idx + ((size_t)b*NQ + s)*K;

    if constexpr (RECOMP){
        float cx = center[b*3+0], cy = center[b*3+1], cz = center[b*3+2];
        if (lane < K){
            int myi = kix[lane];
            const float* xp = xyz + ((size_t)b*16384 + myi)*3;
            s_pts[wid][lane][0] = xp[0]-cx;
            s_pts[wid][lane][1] = xp[1]-cy;
            s_pts[wid][lane][2] = xp[2]-cz;
            const float* fp = f + ((size_t)b*16384 + myi)*3;
            s_pts[wid][lane][3] = fp[0];
            s_pts[wid][lane][4] = fp[1];
            s_pts[wid][lane][5] = fp[2];
        }
        #pragma unroll
        for (int k=0; k<K; ++k){
            float gv = conv_feat6(s_pts[wid][k][0], s_pts[wid][k][1], s_pts[wid][k][2],
                                  s_pts[wid][k][3], s_pts[wid][k][4], s_pts[wid][k][5],
                                  cwT[0*64+lane], cwT[1*64+lane], cwT[2*64+lane],
                                  cwT[3*64+lane], cwT[4*64+lane], cwT[5*64+lane],
                                  s_csc[lane], s_cbs[lane]);
            gda[wid][k][lane] = gv - np_o;
        }
    } else {
        int myi = kix[lane < K ? lane : 0];
        #pragma unroll
        for (int k=0; k<K; ++k){
            int ik = __shfl(myi, k, 64);
            gda[wid][k][lane] = src_feat[((size_t)b*NSRC + ik)*64 + lane] - np_o;
        }
    }

    float C = 0.f;
    #pragma unroll
    for (int d=0; d<64; d++) C = fmaf(np_l[wid][d], wt[(64+d)*65 + lane], C);

    float acc_y[K];
    #pragma unroll
    for (int k=0;k<K;k++) acc_y[k] = C;

    #pragma unroll
    for (int c=0; c<2; ++c){
        float wr[32];
        #pragma unroll
        for (int j=0;j<32;j++) wr[j] = wt[(c*32+j)*65 + lane];
        #pragma unroll
        for (int k=0;k<K;k++){
            const float4* g4 = (const float4*)&gda[wid][k][c*32];
            float yk = 0.f;
            #pragma unroll
            for (int j4=0;j4<8;j4++){
                float4 gg = g4[j4];
                yk = fmaf(gg.x, wr[j4*4+0], yk);
                yk = fmaf(gg.y, wr[j4*4+1], yk);
                yk = fmaf(gg.z, wr[j4*4+2], yk);
                yk = fmaf(gg.w, wr[j4*4+3], yk);
            }
            acc_y[k] = acc_y[k] + yk;
        }
    }

    float acc = -1e30f;
    #pragma unroll
    for (int k=0;k<K;k++){
        float v = fmaxf(fmaf(acc_y[k], s_sc[lane], s_bs[lane]), 0.0f);
        acc = fmaxf(acc, v);
    }
    out[((size_t)b*NQ + s)*64 + lane] = acc;
}

// ===================== sa_block (1024-thr, wave-parallel softmax) =====================
__device__ void sa_block(const float* X, float* Xout,
                         float* Q, float* E, float* XV, float* XR, float* CS,
                         const float* qk_w, const float* v_w, const float* v_b,
                         const float* t_w, const float* t_b,
                         const float* g, const float* bb, int t)
{
    constexpr int NT = 1024;
    for (int e=t; e<512; e+=NT){
        int n = e>>4, o = e&15;
        float y = 0.f;
        for (int c=0;c<64;c++) y = fmaf(qk_w[o*64+c], X[c*32+n], y);
        Q[n*16+o] = y;
    }
    for (int e=t; e<2048; e+=NT){
        int o = e>>5, n = e&31;
        float y = v_b[o];
        for (int c=0;c<64;c++) y = fmaf(v_w[o*64+c], X[c*32+n], y);
        XV[o*32+n] = y;
    }
    __syncthreads();
    // energy: element e = t  (n = t>>5, m = t&31)
    {
        int n = t>>5, m = t&31;
        float y = 0.f;
        for (int d=0;d<16;d++) y = fmaf(Q[n*16+d], Q[m*16+d], y);
        E[t] = y;
    }
    __syncthreads();
    // wave-parallel row softmax (rows are 32-lane groups; shfl_xor mask<32
    // stays within the group). max is order-invariant; sum order differs
    // from sequential by last-ulp only (continuous path).
    {
        float v = E[t];
        float mx = v;
        #pragma unroll
        for (int mk=16; mk>=1; mk>>=1) mx = fmaxf(mx, __shfl_xor(mx, mk, 64));
        float p = expf(v - mx);
        float sum = p;
        #pragma unroll
        for (int mk=16; mk>=1; mk>>=1) sum += __shfl_xor(sum, mk, 64);
        E[t] = p / sum;
    }
    __syncthreads();
    if (t < 32){
        float cs = 0.f;
        for (int n=0;n<32;n++) cs += E[n*32+t];
        CS[t] = 1e-9f + cs;
    }
    __syncthreads();
    E[t] = E[t] / CS[t&31];
    __syncthreads();
    for (int e=t; e<2048; e+=NT){
        int c = e>>5, m = e&31;
        float y = 0.f;
        for (int n=0;n<32;n++) y = fmaf(XV[c*32+n], E[n*32+m], y);
        XR[c*32+m] = y;
    }
    __syncthreads();
    for (int e=t; e<2048; e+=NT){
        int o = e>>5, n = e&31;
        float y = 0.f;
        for (int c=0;c<64;c++) y = fmaf(t_w[o*64+c], X[c*32+n]-XR[c*32+n], y);
        y += t_b[o];
        y = fmaxf(fmaf(y, bnscale(g[o]), bb[o]), 0.0f);
        Xout[e] = X[e] + y;
    }
    __syncthreads();
}

// ===================== k_mega =====================
// fps2 + gather2 + knn2 + group_local<16> + tail, fused. One block per batch.
// v2: 1024 threads (16 waves, 4/SIMD) for latency hiding; F1/FO padded to
// stride 33 (kills 64-way bank conflicts); gda aliased into tail scratch.
__global__ __launch_bounds__(1024) void k_mega(
    const float* __restrict__ new_xyz1,   // (b,128,3) centered
    const float* __restrict__ feat,       // (b,128,64)
    const float* __restrict__ l1_w, const float* __restrict__ l1_g, const float* __restrict__ l1_b,
    const float* st_c1_w, const float* st_bn1_g, const float* st_bn1_b,
    const float* st_c2_w, const float* st_bn2_g, const float* st_bn2_b,
    const float* sa1_qk, const float* sa1_v, const float* sa1_vb,
    const float* sa1_t, const float* sa1_tb, const float* sa1_g, const float* sa1_b,
    const float* sa2_qk, const float* sa2_v, const float* sa2_vb,
    const float* sa2_t, const float* sa2_tb, const float* sa2_g, const float* sa2_b,
    const float* fuse_w, const float* fuse_g, const float* fuse_b,
    const float* lin1_w, const float* bn6_g, const float* bn6_b,
    const float* lin2_w, const float* lin2_b,
    float* __restrict__ out)
{
    constexpr int NT = 1024;
    __shared__ float nx1[384];            // new_xyz1[b] (128,3)
    __shared__ int   s_i2[32];            // fps2 indices
    __shared__ float np2L[2048];          // np2 (32,64)
    __shared__ float nx2[96];             // new_xyz2 (32,3)
    __shared__ int   s_k2[512];           // knn2 (32,16)
    __shared__ float wt[8320];            // l1_w transposed, stride 65
    __shared__ float s_sc[64], s_bs[64];
    __shared__ float smt[15168];          // tail scratch; F1 (stride 33) at 0

    int b = blockIdx.x, t = threadIdx.x, wid = t>>6, lane = t&63;

    // ---- A: stage ----
    for (int e=t; e<384; e+=NT) nx1[e] = new_xyz1[(size_t)b*384 + e];
    for (int e=t; e<8192; e+=NT){ int o = e>>7, d = e&127; wt[d*65 + o] = l1_w[e]; }
    if (t < 64){ s_sc[t] = bnscale(l1_g[t]); s_bs[t] = l1_b[t]; }
    __syncthreads();

    // ---- B: fps2 (128 -> 32), wave 0 only ----
    if (wid == 0){
        float px[2],py[2],pz[2],dist[2];
        #pragma unroll
        for (int i=0;i<2;i++){
            int n = lane + i*64;
            px[i]=nx1[n*3+0]; py[i]=nx1[n*3+1]; pz[i]=nx1[n*3+2];
            dist[i]=1e10f;
        }
        if (lane==0) s_i2[0] = 0;
        float cx=nx1[0], cy=nx1[1], cz=nx1[2];
        for (int it=1; it<32; ++it){
            float bv=-1.0f; int bi=0;
            float bx=0.f, by=0.f, bz=0.f;
            #pragma unroll
            for (int i=0;i<2;i++){
                float d = fpsdist(px[i]-cx, py[i]-cy, pz[i]-cz);
                float nd = fminf(dist[i], d);
                dist[i]=nd;
                bool better = nd > bv;
                bv = better ? nd : bv;
                bi = better ? (lane + i*64) : bi;
                bx = better ? px[i] : bx;
                by = better ? py[i] : by;
                bz = better ? pz[i] : bz;
            }
            unsigned long long key = ((unsigned long long)__float_as_uint(bv) << 32)
                                   | (unsigned long long)(unsigned)(~(unsigned)bi);
            #pragma unroll
            for (int off=32; off>=1; off>>=1){
                unsigned long long ok = u64_shfl_down(key, off);
                float ox = __shfl_down(bx, off, 64);
                float oy = __shfl_down(by, off, 64);
                float oz = __shfl_down(bz, off, 64);
                bool better = ok > key;
                key = better ? ok : key;
                bx = better ? ox : bx;
                by = better ? oy : by;
                bz = better ? oz : bz;
            }
            key = u64_bcast0(key);
            cx = __shfl(bx, 0, 64); cy = __shfl(by, 0, 64); cz = __shfl(bz, 0, 64);
            if (lane==0) s_i2[it] = (int)(~(unsigned)(key & 0xFFFFFFFFull));
        }
    }
    __syncthreads();

    // ---- C: gather2 ----
    for (int e=t; e<2048; e+=NT){
        int s = e>>6, o = e&63;
        np2L[s*64 + o] = feat[((size_t)b*128 + s_i2[s])*64 + o];
    }
    if (t < 32){
        int idx = s_i2[t];
        nx2[t*3+0] = nx1[idx*3+0];
        nx2[t*3+1] = nx1[idx*3+1];
        nx2[t*3+2] = nx1[idx*3+2];
    }
    __syncthreads();

    // ---- D: knn2 (32 queries x top-16 of 128), 2 queries per wave ----
    for (int j=0;j<2;j++){
        int s = wid + 16*j;
        float qx = nx2[s*3+0], qy = nx2[s*3+1], qz = nx2[s*3+2];
        float qs = sumsq3(qx,qy,qz);
        unsigned long long pp0, pp1;
        {
            float ax=nx1[lane*3+0], ay=nx1[lane*3+1], az=nx1[lane*3+2];
            pp0 = packdi(sqdist3(qx,qy,qz,qs,ax,ay,az), (unsigned)lane);
            ax=nx1[(lane+64)*3+0]; ay=nx1[(lane+64)*3+1]; az=nx1[(lane+64)*3+2];
            pp1 = packdi(sqdist3(qx,qy,qz,qs,ax,ay,az), (unsigned)(lane+64));
        }
        for (int r=0; r<16; ++r){
            unsigned long long mm = u64min(pp0, pp1);
            #pragma unroll
            for (int off=32; off>=1; off>>=1) mm = u64min(mm, u64_shfl_down(mm, off));
            unsigned long long win = u64_bcast0(mm);
            if (lane==0) s_k2[s*16 + r] = (int)(win & 0xFFFFFFFFull);
            if (pp0 == win) pp0 = ~0ull;
            if (pp1 == win) pp1 = ~0ull;
        }
    }
    __syncthreads();

    // ---- E: group_local<16>, 2 queries per wave, k in two 8-halves ----
    // gda aliases smt[2112..10304) (XA..XV region, unused until tail)
    float* gda = smt + 2112;
    for (int j=0;j<2;j++){
        int s = wid + 16*j;
        float np_o = np2L[s*64 + lane];
        float C0 = 0.f;
        #pragma unroll
        for (int d=0; d<64; d++) C0 = fmaf(np2L[s*64 + d], wt[(64+d)*65 + lane], C0);
        float acc_y[16];
        #pragma unroll
        for (int k=0;k<16;k++) acc_y[k] = C0;
        #pragma unroll
        for (int half=0; half<2; ++half){
            #pragma unroll
            for (int kk=0;kk<8;++kk){
                int ik = s_k2[s*16 + half*8 + kk];
                gda[(wid*8+kk)*64 + lane] = feat[((size_t)b*128 + ik)*64 + lane] - np_o;
            }
            #pragma unroll
            for (int c=0; c<2; ++c){
                float wr[32];
                #pragma unroll
                for (int jj=0;jj<32;jj++) wr[jj] = wt[(c*32+jj)*65 + lane];
                #pragma unroll
                for (int kk=0;kk<8;++kk){
                    const float4* g4 = (const float4*)&gda[(wid*8+kk)*64 + c*32];
                    float yk = 0.f;
                    #pragma unroll
                    for (int j4=0;j4<8;j4++){
                        float4 gg = g4[j4];
                        yk = fmaf(gg.x, wr[j4*4+0], yk);
                        yk = fmaf(gg.y, wr[j4*4+1], yk);
                        yk = fmaf(gg.z, wr[j4*4+2], yk);
                        yk = fmaf(gg.w, wr[j4*4+3], yk);
                    }
                    acc_y[half*8+kk] = acc_y[half*8+kk] + yk;
                }
            }
        }
        float acc = -1e30f;
        #pragma unroll
        for (int k=0;k<16;k++){
            float v = fmaxf(fmaf(acc_y[k], s_sc[lane], s_bs[lane]), 0.0f);
            acc = fmaxf(acc, v);
        }
        smt[lane*33 + s] = acc;     // F1[c=lane][n=s], stride 33 (conflict-free)
    }
    __syncthreads();

    // ---- F: tail ----
    float* F1 = smt;            // stride 33, [0,2112)
    float* XA = smt + 2112;     // 2048
    float* XB = smt + 4160;     // 2048
    float* Q  = smt + 6208;     // 512
    float* E  = smt + 6720;     // 1024
    float* XV = smt + 7744;     // 2048
    float* XR = smt + 9792;     // 2048
    float* CS = smt + 11840;    // 32
    float* FO = smt + 6208;     // 256x33 = 8448 (reuses SA scratch)
    float* PO = smt + 14656;    // 256
    float* P2 = smt + 14912;    // 256

    for (int e=t; e<2048; e+=NT){
        int o = e>>5, n = e&31;
        float y = 0.f;
        for (int c=0;c<64;c++) y = fmaf(st_c1_w[o*64+c], F1[c*33+n], y);
        XA[e] = fmaxf(fmaf(y, bnscale(st_bn1_g[o]), st_bn1_b[o]), 0.0f);
    }
    __syncthreads();
    for (int e=t; e<2048; e+=NT){
        int o = e>>5, n = e&31;
        float y = 0.f;
        for (int c=0;c<64;c++) y = fmaf(st_c2_w[o*64+c], XA[c*32+n], y);
        XB[e] = fmaxf(fmaf(y, bnscale(st_bn2_g[o]), st_bn2_b[o]), 0.0f);
    }
    __syncthreads();
    sa_block(XB, XA, Q,E,XV,XR,CS, sa1_qk, sa1_v, sa1_vb, sa1_t, sa1_tb, sa1_g, sa1_b, t);
    sa_block(XA, XB, Q,E,XV,XR,CS, sa2_qk, sa2_v, sa2_vb, sa2_t, sa2_tb, sa2_g, sa2_b, t);
    for (int e=t; e<8192; e+=NT){
        int o = e>>5, n = e&31;
        const float* wr = fuse_w + o*192;
        float y = 0.f;
        for (int c=0;c<64;c++) y = fmaf(wr[c],      XA[c*32+n], y);
        for (int c=0;c<64;c++) y = fmaf(wr[64+c],   XB[c*32+n], y);
        for (int c=0;c<64;c++) y = fmaf(wr[128+c],  F1[c*33+n], y);
        float v = fmaf(y, bnscale(fuse_g[o]), fuse_b[o]);
        FO[o*33+n] = (v > 0.0f) ? v : 0.2f*v;
    }
    __syncthreads();
    if (t < 256){
        float mx = -1e30f;
        for (int n=0;n<32;n++) mx = fmaxf(mx, FO[t*33+n]);
        PO[t] = mx;
    }
    __syncthreads();
    if (t < 256){
        const float* wr = lin1_w + t*256;
        float y = 0.f;
        for (int c=0;c<256;c++) y = fmaf(wr[c], PO[c], y);
        P2[t] = fmaxf(fmaf(y, bnscale(bn6_g[t]), bn6_b[t]), 0.0f);
    }
    __syncthreads();
    if (t < 256){
        const float* wr = lin2_w + t*256;
        float y = 0.f;
        for (int c=0;c<256;c++) y = fmaf(wr[c], P2[c], y);
        out[96 + b*256 + t] = y + lin2_b[t];
    }
}

// ===================== launch =====================
extern "C" void kernel_launch(void* const* d_in, const int* in_sizes, int n_in,
                              void* d_out, int out_size, void* d_ws, size_t ws_size,
                              hipStream_t stream)
{
    const float* xyz      = (const float*)d_in[0];
    const float* f        = (const float*)d_in[1];
    const float* conv1_w  = (const float*)d_in[2];
    const float* bn1_g    = (const float*)d_in[3];
    const float* bn1_b    = (const float*)d_in[4];
    const float* l0_w     = (const float*)d_in[5];
    const float* l0_g     = (const float*)d_in[6];
    const float* l0_b     = (const float*)d_in[7];
    const float* l1_w     = (const float*)d_in[8];
    const float* l1_g     = (const float*)d_in[9];
    const float* l1_b     = (const float*)d_in[10];
    const float* st_c1_w  = (const float*)d_in[11];
    const float* st_bn1_g = (const float*)d_in[12];
    const float* st_bn1_b = (const float*)d_in[13];
    const float* st_c2_w  = (const float*)d_in[14];
    const float* st_bn2_g = (const float*)d_in[15];
    const float* st_bn2_b = (const float*)d_in[16];
    const float* sa1_qk   = (const float*)d_in[17];
    const float* sa1_v    = (const float*)d_in[18];
    const float* sa1_vb   = (const float*)d_in[19];
    const float* sa1_t    = (const float*)d_in[20];
    const float* sa1_tb   = (const float*)d_in[21];
    const float* sa1_g    = (const float*)d_in[22];
    const float* sa1_b    = (const float*)d_in[23];
    const float* sa2_qk   = (const float*)d_in[24];
    const float* sa2_v    = (const float*)d_in[25];
    const float* sa2_vb   = (const float*)d_in[26];
    const float* sa2_t    = (const float*)d_in[27];
    const float* sa2_tb   = (const float*)d_in[28];
    const float* sa2_g    = (const float*)d_in[29];
    const float* sa2_b    = (const float*)d_in[30];
    const float* fuse_w   = (const float*)d_in[31];
    const float* fuse_g   = (const float*)d_in[32];
    const float* fuse_b   = (const float*)d_in[33];
    const float* lin1_w   = (const float*)d_in[34];
    const float* bn6_g    = (const float*)d_in[35];
    const float* bn6_b    = (const float*)d_in[36];
    const float* lin2_w   = (const float*)d_in[37];
    const float* lin2_b   = (const float*)d_in[38];
    float* out = (float*)d_out;

    float* ws = (float*)d_ws;
    float* center   = ws + 0;        // 96
    float* new_xyz1 = ws + 96;       // 12288
    float* np1      = ws + 12384;    // 262144
    float* feat     = ws + 274528;   // 262144
    int*   fps1     = (int*)(ws + 536672);  // 4096
    int*   knn1     = (int*)(ws + 540768);  // 131072

    k_fps1<<<32, 1024, 0, stream>>>(xyz, center, out, fps1);
    k_knn1<<<1024, 256, 0, stream>>>(xyz, f, center, conv1_w, bn1_g, bn1_b,
                                     fps1, new_xyz1, np1, knn1);
    k_group_local<32,128,1,true><<<1024, 256, 0, stream>>>(
        xyz, f, center, conv1_w, bn1_g, bn1_b, nullptr, knn1, np1, l0_w, l0_g, l0_b, feat);
    k_mega<<<32, 1024, 0, stream>>>(new_xyz1, feat,
        l1_w, l1_g, l1_b,
        st_c1_w, st_bn1_g, st_bn1_b, st_c2_w, st_bn2_g, st_bn2_b,
        sa1_qk, sa1_v, sa1_vb, sa1_t, sa1_tb, sa1_g, sa1_b,
        sa2_qk, sa2_v, sa2_vb, sa2_t, sa2_tb, sa2_g, sa2_b,
        fuse_w, fuse_g, fuse_b, lin1_w, bn6_g, bn6_b, lin2_w, lin2_b, out);
}